// Round 1
// baseline (30609.726 us; speedup 1.0000x reference)
//
#include <hip/hip_runtime.h>
#include <hip/hip_bf16.h>

#define NLAYER 12
#define NH 12
#define DH 64
#define DMODEL 768
#define DI 3072
#define NV 10000
#define QLEN 512
#define MLEN 512
#define CLEN 32
#define BSZ 4
#define KLEN (CLEN + MLEN + QLEN)   // 1056
#define MQ (QLEN * BSZ)             // 2048
#define MK (KLEN * BSZ)             // 4224
#define H3 (3 * NH * DH)            // 2304
#define HD (NH * DH)                // 768

// ---------------- embedding: h = emb[x] * sqrt(D) ----------------
__global__ __launch_bounds__(256) void k_embed(const int* __restrict__ x,
                                               const float* __restrict__ emb,
                                               float* __restrict__ h) {
    int idx = blockIdx.x * 256 + threadIdx.x;
    if (idx >= MQ * DMODEL) return;
    int row = idx / DMODEL;     // i*BSZ + b
    int d = idx % DMODEL;
    int tok = x[row];
    h[idx] = emb[(size_t)tok * DMODEL + d] * 27.712812921102035f;  // sqrt(768)
}

// ---------------- sinusoidal position embedding r[KLEN][D] ----------------
__global__ __launch_bounds__(256) void k_posemb(float* __restrict__ r) {
    int idx = blockIdx.x * 256 + threadIdx.x;
    if (idx >= KLEN * DMODEL) return;
    int k = idx / DMODEL;
    int d = idx % DMODEL;
    int pos = KLEN - 1 - k;
    int j = (d < DMODEL / 2) ? d : d - DMODEL / 2;
    double inv = exp(-((double)(2 * j) / (double)DMODEL) * log(10000.0));
    double s = (double)pos * inv;
    r[idx] = (d < DMODEL / 2) ? (float)sin(s) : (float)cos(s);
}

// ---------------- concat [condition; mems[l]; h] ----------------
__global__ __launch_bounds__(256) void k_concat(const float* __restrict__ cond,
                                                const float* __restrict__ mem_l,
                                                const float* __restrict__ h,
                                                float* __restrict__ cat) {
    int idx = blockIdx.x * 256 + threadIdx.x;
    if (idx >= MK * DMODEL) return;
    int row = idx / DMODEL;     // k*BSZ + b
    int k = row / BSZ;
    float v;
    if (k < CLEN) v = cond[idx];
    else if (k < CLEN + MLEN) v = mem_l[idx - CLEN * BSZ * DMODEL];
    else v = h[idx - (CLEN + MLEN) * BSZ * DMODEL];
    cat[idx] = v;
}

// ---------------- fp32 tiled GEMM: C[M,N] = A[M,K] @ B[K,N] (+bias)(+relu) ----------------
// K must be a multiple of 16; N a multiple of 4.
template <bool BIAS, bool RELU>
__global__ __launch_bounds__(256) void k_gemm(const float* __restrict__ A,
                                              const float* __restrict__ B,
                                              const float* __restrict__ bias,
                                              float* __restrict__ C,
                                              int M, int N, int K) {
    __shared__ float As[16][64];   // As[k][m]
    __shared__ float Bs[16][64];   // Bs[k][n]
    int tid = threadIdx.x;
    int bm = blockIdx.y * 64, bn = blockIdx.x * 64;
    int ty = tid >> 4, tx = tid & 15;
    float acc[4][4] = {};
    int arow = tid >> 2, ak = (tid & 3) * 4;
    int bk = tid >> 4, bc = (tid & 15) * 4;
    for (int k0 = 0; k0 < K; k0 += 16) {
        float4 av = make_float4(0.f, 0.f, 0.f, 0.f);
        if (bm + arow < M) av = *(const float4*)(A + (size_t)(bm + arow) * K + k0 + ak);
        float4 bv = make_float4(0.f, 0.f, 0.f, 0.f);
        if (bn + bc < N) bv = *(const float4*)(B + (size_t)(k0 + bk) * N + bn + bc);
        As[ak + 0][arow] = av.x; As[ak + 1][arow] = av.y;
        As[ak + 2][arow] = av.z; As[ak + 3][arow] = av.w;
        Bs[bk][bc + 0] = bv.x; Bs[bk][bc + 1] = bv.y;
        Bs[bk][bc + 2] = bv.z; Bs[bk][bc + 3] = bv.w;
        __syncthreads();
#pragma unroll
        for (int kk = 0; kk < 16; kk++) {
            float a[4], bb[4];
#pragma unroll
            for (int t = 0; t < 4; t++) a[t] = As[kk][ty * 4 + t];
#pragma unroll
            for (int t = 0; t < 4; t++) bb[t] = Bs[kk][tx * 4 + t];
#pragma unroll
            for (int ii = 0; ii < 4; ii++)
#pragma unroll
                for (int jj = 0; jj < 4; jj++)
                    acc[ii][jj] += a[ii] * bb[jj];
        }
        __syncthreads();
    }
#pragma unroll
    for (int ii = 0; ii < 4; ii++) {
        int m = bm + ty * 4 + ii;
        if (m >= M) continue;
#pragma unroll
        for (int jj = 0; jj < 4; jj++) {
            int n = bn + tx * 4 + jj;
            if (n >= N) continue;
            float v = acc[ii][jj];
            if (BIAS) v += bias[n];
            if (RELU) v = fmaxf(v, 0.0f);
            C[(size_t)m * N + n] = v;
        }
    }
}

// ---------------- fused rel-attention: scores + softmax + A@V ----------------
// grid: (QLEN/QT, NH, BSZ), block 256
#define QT 8
__global__ __launch_bounds__(256) void k_attn(const float* __restrict__ heads,
                                              const float* __restrict__ rk,
                                              const float* __restrict__ rwb,
                                              const float* __restrict__ rrb,
                                              float* __restrict__ attn) {
    __shared__ float sc[QT][KLEN];                       // 33.8 KB
    __shared__ __align__(16) float qw[QT][DH];
    __shared__ __align__(16) float qr[QT][DH];
    __shared__ float red[QT][32];
    int tid = threadIdx.x;
    int qt0 = blockIdx.x * QT;
    int n = blockIdx.y;
    int b = blockIdx.z;

    // load Q tile (+biases)
    for (int idx = tid; idx < QT * DH; idx += 256) {
        int qi = idx >> 6, d = idx & 63;
        int i = qt0 + qi;
        float q = heads[((size_t)((CLEN + MLEN + i) * BSZ + b)) * H3 + n * DH + d];
        qw[qi][d] = q + rwb[n * DH + d];
        qr[qi][d] = q + rrb[n * DH + d];
    }
    __syncthreads();

    // scores: AC + shifted BD, masked -> 0 (excluded from softmax below)
    for (int idx = tid; idx < QT * KLEN; idx += 256) {
        int qi = idx / KLEN;
        int j = idx % KLEN;
        int i = qt0 + qi;
        if (j <= i + CLEN + MLEN) {
            const float4* kp = (const float4*)(heads + ((size_t)j * BSZ + b) * H3 + HD + n * DH);
            const float4* rp = (const float4*)(rk + (size_t)(j + QLEN - 1 - i) * HD + n * DH);
            const float4* qwp = (const float4*)qw[qi];
            const float4* qrp = (const float4*)qr[qi];
            float ac = 0.f, bd = 0.f;
#pragma unroll
            for (int dd = 0; dd < DH / 4; dd++) {
                float4 kv = kp[dd], rv = rp[dd], q1 = qwp[dd], q2 = qrp[dd];
                ac += q1.x * kv.x + q1.y * kv.y + q1.z * kv.z + q1.w * kv.w;
                bd += q2.x * rv.x + q2.y * rv.y + q2.z * rv.z + q2.w * rv.w;
            }
            sc[qi][j] = (ac + bd) * 0.125f;
        } else {
            sc[qi][j] = 0.0f;
        }
    }
    __syncthreads();

    // softmax per query row over valid length
    {
        int row = tid >> 5, lane = tid & 31;
        int i = qt0 + row;
        int len = i + CLEN + MLEN + 1;
        float m = -1e30f;
        for (int j = lane; j < len; j += 32) m = fmaxf(m, sc[row][j]);
        red[row][lane] = m;
        __syncthreads();
#pragma unroll
        for (int t = 0; t < 32; t++) m = fmaxf(m, red[row][t]);
        float ssum = 0.f;
        for (int j = lane; j < len; j += 32) {
            float p = expf(sc[row][j] - m);
            sc[row][j] = p;
            ssum += p;
        }
        __syncthreads();
        red[row][lane] = ssum;
        __syncthreads();
        float tot = 0.f;
#pragma unroll
        for (int t = 0; t < 32; t++) tot += red[row][t];
        float inv = 1.0f / tot;
        for (int j = lane; j < len; j += 32) sc[row][j] *= inv;
    }
    __syncthreads();

    // A@V: each 32-thread group handles one query row, 2 dims/thread
    {
        int qi = tid >> 5, lane = tid & 31;
        int d0 = lane * 2;
        int i = qt0 + qi;
        int len = i + CLEN + MLEN + 1;
        const float* vb = heads + (size_t)b * H3 + 2 * HD + n * DH + d0;
        float a0 = 0.f, a1 = 0.f;
        for (int j = 0; j < len; j++) {
            float p = sc[qi][j];
            float2 vv = *(const float2*)(vb + (size_t)j * BSZ * H3);
            a0 += p * vv.x;
            a1 += p * vv.y;
        }
        float2* op = (float2*)(attn + ((size_t)i * BSZ + b) * HD + n * DH + d0);
        *op = make_float2(a0, a1);
    }
}

// ---------------- h = LN(h + delta) * g + b ----------------
__global__ __launch_bounds__(256) void k_add_ln(float* __restrict__ h,
                                                const float* __restrict__ delta,
                                                const float* __restrict__ g,
                                                const float* __restrict__ bta) {
    __shared__ float xs[DMODEL];
    __shared__ float red[256];
    int row = blockIdx.x;
    int tid = threadIdx.x;
    float* hr = h + (size_t)row * DMODEL;
    const float* dr = delta + (size_t)row * DMODEL;
    float s = 0.f;
    for (int d = tid; d < DMODEL; d += 256) {
        float v = hr[d] + dr[d];
        xs[d] = v;
        s += v;
    }
    red[tid] = s;
    __syncthreads();
    for (int st = 128; st > 0; st >>= 1) {
        if (tid < st) red[tid] += red[tid + st];
        __syncthreads();
    }
    float mean = red[0] * (1.0f / DMODEL);
    __syncthreads();
    float v2 = 0.f;
    for (int d = tid; d < DMODEL; d += 256) {
        float t = xs[d] - mean;
        v2 += t * t;
    }
    red[tid] = v2;
    __syncthreads();
    for (int st = 128; st > 0; st >>= 1) {
        if (tid < st) red[tid] += red[tid + st];
        __syncthreads();
    }
    float inv = rsqrtf(red[0] * (1.0f / DMODEL) + 1e-5f);
    for (int d = tid; d < DMODEL; d += 256) {
        hr[d] = (xs[d] - mean) * inv * g[d] + bta[d];
    }
}

extern "C" void kernel_launch(void* const* d_in, const int* in_sizes, int n_in,
                              void* d_out, int out_size, void* d_ws, size_t ws_size,
                              hipStream_t stream) {
    const int* x = (const int*)d_in[0];
    const float* condition = (const float*)d_in[1];
    const float* mems = (const float*)d_in[2];
    const float* emb = (const float*)d_in[3];
    const float* qkv_w = (const float*)d_in[4];
    const float* r_net_w = (const float*)d_in[5];
    const float* o_w = (const float*)d_in[6];
    const float* ln1_g = (const float*)d_in[7];
    const float* ln1_b = (const float*)d_in[8];
    const float* w1 = (const float*)d_in[9];
    const float* b1 = (const float*)d_in[10];
    const float* w2 = (const float*)d_in[11];
    const float* b2 = (const float*)d_in[12];
    const float* ln2_g = (const float*)d_in[13];
    const float* ln2_b = (const float*)d_in[14];
    const float* r_w_bias = (const float*)d_in[15];
    const float* r_r_bias = (const float*)d_in[16];
    const float* proj_w = (const float*)d_in[17];
    const float* proj_b = (const float*)d_in[18];
    float* out = (float*)d_out;

    float* ws = (float*)d_ws;
    float* h = ws;                                   // 2048*768
    float* rbuf = h + (size_t)MQ * DMODEL;           // 1056*768
    float* rk = rbuf + (size_t)KLEN * DMODEL;        // 1056*768
    float* attnb = rk + (size_t)KLEN * HD;           // 2048*768
    float* cat = attnb + (size_t)MQ * HD;            // 4224*768   (delta aliases cat)
    float* heads = cat + (size_t)MK * DMODEL;        // 4224*2304  (ffn aliases heads)
    float* delta = cat;                              // 2048*768 reuse
    float* ffn = heads;                              // 2048*3072 reuse

    dim3 blk(256);
    k_embed<<<dim3((MQ * DMODEL + 255) / 256), blk, 0, stream>>>(x, emb, h);
    k_posemb<<<dim3((KLEN * DMODEL + 255) / 256), blk, 0, stream>>>(rbuf);

    for (int l = 0; l < NLAYER; l++) {
        k_concat<<<dim3((MK * DMODEL + 255) / 256), blk, 0, stream>>>(
            condition, mems + (size_t)l * MLEN * BSZ * DMODEL, h, cat);

        // heads = cat @ qkv_w[l]           [4224,2304]
        k_gemm<false, false><<<dim3(H3 / 64, MK / 64), blk, 0, stream>>>(
            cat, qkv_w + (size_t)l * DMODEL * H3, nullptr, heads, MK, H3, DMODEL);

        // rk = r @ r_net_w[l]              [1056,768]
        k_gemm<false, false><<<dim3(HD / 64, (KLEN + 63) / 64), blk, 0, stream>>>(
            rbuf, r_net_w + (size_t)l * DMODEL * HD, nullptr, rk, KLEN, HD, DMODEL);

        // fused attention -> attnb         [2048,768]
        k_attn<<<dim3(QLEN / QT, NH, BSZ), blk, 0, stream>>>(
            heads, rk, r_w_bias, r_r_bias, attnb);

        // delta = attnb @ o_w[l]           [2048,768]
        k_gemm<false, false><<<dim3(DMODEL / 64, MQ / 64), blk, 0, stream>>>(
            attnb, o_w + (size_t)l * HD * DMODEL, nullptr, delta, MQ, DMODEL, HD);

        // h = LN(h + delta)
        k_add_ln<<<dim3(MQ), blk, 0, stream>>>(h, delta, ln1_g + (size_t)l * DMODEL,
                                               ln1_b + (size_t)l * DMODEL);

        // ffn = relu(h @ w1[l] + b1[l])    [2048,3072]
        k_gemm<true, true><<<dim3(DI / 64, MQ / 64), blk, 0, stream>>>(
            h, w1 + (size_t)l * DMODEL * DI, b1 + (size_t)l * DI, ffn, MQ, DI, DMODEL);

        // delta = ffn @ w2[l] + b2[l]      [2048,768]
        k_gemm<true, false><<<dim3(DMODEL / 64, MQ / 64), blk, 0, stream>>>(
            ffn, w2 + (size_t)l * DI * DMODEL, b2 + (size_t)l * DMODEL, delta, MQ, DMODEL, DI);

        // h = LN(h + delta)
        k_add_ln<<<dim3(MQ), blk, 0, stream>>>(h, delta, ln2_g + (size_t)l * DMODEL,
                                               ln2_b + (size_t)l * DMODEL);
    }

    // out = h @ proj_w + proj_b            [2048,10000]
    k_gemm<true, false><<<dim3((NV + 63) / 64, MQ / 64), blk, 0, stream>>>(
        h, proj_w, proj_b, out, MQ, NV, DMODEL);
}

// Round 2
// 12551.468 us; speedup vs baseline: 2.4387x; 2.4387x over previous
//
#include <hip/hip_runtime.h>
#include <hip/hip_bf16.h>

#define NLAYER 12
#define NH 12
#define DH 64
#define DMODEL 768
#define DI 3072
#define NV 10000
#define QLEN 512
#define MLEN 512
#define CLEN 32
#define BSZ 4
#define KLEN (CLEN + MLEN + QLEN)   // 1056
#define MQ (QLEN * BSZ)             // 2048
#define MK (KLEN * BSZ)             // 4224
#define H3 (3 * NH * DH)            // 2304
#define HD (NH * DH)                // 768
#define NG (BSZ * NH)               // 48 batched-attention groups
#define SROW ((size_t)QLEN * KLEN)  // score elems per group: 512*1056

// ---------------- embedding: h = emb[x] * sqrt(D) ----------------
__global__ __launch_bounds__(256) void k_embed(const int* __restrict__ x,
                                               const float* __restrict__ emb,
                                               float* __restrict__ h) {
    int idx = blockIdx.x * 256 + threadIdx.x;
    if (idx >= MQ * DMODEL) return;
    int row = idx / DMODEL;
    int d = idx % DMODEL;
    int tok = x[row];
    h[idx] = emb[(size_t)tok * DMODEL + d] * 27.712812921102035f;  // sqrt(768)
}

// ---------------- sinusoidal position embedding r[KLEN][D] ----------------
__global__ __launch_bounds__(256) void k_posemb(float* __restrict__ r) {
    int idx = blockIdx.x * 256 + threadIdx.x;
    if (idx >= KLEN * DMODEL) return;
    int k = idx / DMODEL;
    int d = idx % DMODEL;
    int pos = KLEN - 1 - k;
    int j = (d < DMODEL / 2) ? d : d - DMODEL / 2;
    double inv = exp(-((double)(2 * j) / (double)DMODEL) * log(10000.0));
    double s = (double)pos * inv;
    r[idx] = (d < DMODEL / 2) ? (float)sin(s) : (float)cos(s);
}

// ---------------- concat [condition; mems[l]; h] ----------------
__global__ __launch_bounds__(256) void k_concat(const float* __restrict__ cond,
                                                const float* __restrict__ mem_l,
                                                const float* __restrict__ h,
                                                float* __restrict__ cat) {
    int idx = blockIdx.x * 256 + threadIdx.x;
    if (idx >= MK * DMODEL) return;
    int row = idx / DMODEL;
    int k = row / BSZ;
    float v;
    if (k < CLEN) v = cond[idx];
    else if (k < CLEN + MLEN) v = mem_l[idx - CLEN * BSZ * DMODEL];
    else v = h[idx - (CLEN + MLEN) * BSZ * DMODEL];
    cat[idx] = v;
}

// ---------------- fp32 tiled GEMM: C[M,N] = A[M,K] @ B[K,N] (+bias)(+relu) ----------------
template <bool BIAS, bool RELU>
__global__ __launch_bounds__(256) void k_gemm(const float* __restrict__ A,
                                              const float* __restrict__ B,
                                              const float* __restrict__ bias,
                                              float* __restrict__ C,
                                              int M, int N, int K) {
    __shared__ float As[16][64];
    __shared__ float Bs[16][64];
    int tid = threadIdx.x;
    int bm = blockIdx.y * 64, bn = blockIdx.x * 64;
    int ty = tid >> 4, tx = tid & 15;
    float acc[4][4] = {};
    int arow = tid >> 2, ak = (tid & 3) * 4;
    int bk = tid >> 4, bc = (tid & 15) * 4;
    for (int k0 = 0; k0 < K; k0 += 16) {
        float4 av = make_float4(0.f, 0.f, 0.f, 0.f);
        if (bm + arow < M) av = *(const float4*)(A + (size_t)(bm + arow) * K + k0 + ak);
        float4 bv = make_float4(0.f, 0.f, 0.f, 0.f);
        if (bn + bc < N) bv = *(const float4*)(B + (size_t)(k0 + bk) * N + bn + bc);
        As[ak + 0][arow] = av.x; As[ak + 1][arow] = av.y;
        As[ak + 2][arow] = av.z; As[ak + 3][arow] = av.w;
        Bs[bk][bc + 0] = bv.x; Bs[bk][bc + 1] = bv.y;
        Bs[bk][bc + 2] = bv.z; Bs[bk][bc + 3] = bv.w;
        __syncthreads();
#pragma unroll
        for (int kk = 0; kk < 16; kk++) {
            float a[4], bb[4];
#pragma unroll
            for (int t = 0; t < 4; t++) a[t] = As[kk][ty * 4 + t];
#pragma unroll
            for (int t = 0; t < 4; t++) bb[t] = Bs[kk][tx * 4 + t];
#pragma unroll
            for (int ii = 0; ii < 4; ii++)
#pragma unroll
                for (int jj = 0; jj < 4; jj++)
                    acc[ii][jj] += a[ii] * bb[jj];
        }
        __syncthreads();
    }
#pragma unroll
    for (int ii = 0; ii < 4; ii++) {
        int m = bm + ty * 4 + ii;
        if (m >= M) continue;
#pragma unroll
        for (int jj = 0; jj < 4; jj++) {
            int n = bn + tx * 4 + jj;
            if (n >= N) continue;
            float v = acc[ii][jj];
            if (BIAS) v += bias[n];
            if (RELU) v = fmaxf(v, 0.0f);
            C[(size_t)m * N + n] = v;
        }
    }
}

// ---------------- q prep: qw = q + r_w_bias, qr = q + r_r_bias ----------------
// layout [b][n][QLEN][DH], g = b*NH+n
__global__ __launch_bounds__(256) void k_qprep(const float* __restrict__ heads,
                                               const float* __restrict__ rwb,
                                               const float* __restrict__ rrb,
                                               float* __restrict__ qw,
                                               float* __restrict__ qr) {
    int idx = blockIdx.x * 256 + threadIdx.x;
    if (idx >= NG * QLEN * DH) return;
    int g = idx >> 15;           // / (512*64)
    int rem = idx & 32767;
    int i = rem >> 6;
    int d = rem & 63;
    int b = g / NH, n = g % NH;
    float q = heads[((size_t)((CLEN + MLEN + i) * BSZ + b)) * H3 + n * DH + d];
    qw[idx] = q + rwb[n * DH + d];
    qr[idx] = q + rrb[n * DH + d];
}

// ---------------- batched NT GEMM: C[g][i][j] (=|+=shifted) sum_d A[g][i][d]*B[g][j][d] --------
// A element (i,d): A + b*sAb + n*sAn + i*lda + d ; B element (j,d): B + b*sBb + n*sBn + j*ldb + d
// SHIFT_ACC: C[i][t-(QLEN-1-i)] += v (rel_shift fused); else C[i][j] = v.
template <bool SHIFT_ACC>
__global__ __launch_bounds__(256) void k_bgemm_nt(const float* __restrict__ A, int lda, int sAb, int sAn,
                                                  const float* __restrict__ B, int ldb, int sBb, int sBn,
                                                  float* __restrict__ C,
                                                  int M, int N, int K) {
    int g = blockIdx.z;
    int b = g / NH, n = g % NH;
    A += (size_t)b * sAb + (size_t)n * sAn;
    B += (size_t)b * sBb + (size_t)n * sBn;
    C += (size_t)g * SROW;
    __shared__ float As[16][64];
    __shared__ float Bs[16][64];
    int tid = threadIdx.x;
    int bm = blockIdx.y * 64, bn = blockIdx.x * 64;
    int ty = tid >> 4, tx = tid & 15;
    float acc[4][4] = {};
    int arow = tid >> 2, ak = (tid & 3) * 4;
    for (int k0 = 0; k0 < K; k0 += 16) {
        float4 av = make_float4(0.f, 0.f, 0.f, 0.f);
        if (bm + arow < M) av = *(const float4*)(A + (size_t)(bm + arow) * lda + k0 + ak);
        float4 bv = make_float4(0.f, 0.f, 0.f, 0.f);
        if (bn + arow < N) bv = *(const float4*)(B + (size_t)(bn + arow) * ldb + k0 + ak);
        As[ak + 0][arow] = av.x; As[ak + 1][arow] = av.y;
        As[ak + 2][arow] = av.z; As[ak + 3][arow] = av.w;
        Bs[ak + 0][arow] = bv.x; Bs[ak + 1][arow] = bv.y;
        Bs[ak + 2][arow] = bv.z; Bs[ak + 3][arow] = bv.w;
        __syncthreads();
#pragma unroll
        for (int kk = 0; kk < 16; kk++) {
            float a[4], bb[4];
#pragma unroll
            for (int t = 0; t < 4; t++) a[t] = As[kk][ty * 4 + t];
#pragma unroll
            for (int t = 0; t < 4; t++) bb[t] = Bs[kk][tx * 4 + t];
#pragma unroll
            for (int ii = 0; ii < 4; ii++)
#pragma unroll
                for (int jj = 0; jj < 4; jj++)
                    acc[ii][jj] += a[ii] * bb[jj];
        }
        __syncthreads();
    }
#pragma unroll
    for (int ii = 0; ii < 4; ii++) {
        int m = bm + ty * 4 + ii;
        if (m >= M) continue;
#pragma unroll
        for (int jj = 0; jj < 4; jj++) {
            int nn = bn + tx * 4 + jj;
            if (nn >= N) continue;
            if (SHIFT_ACC) {
                int j = nn - (QLEN - 1) + m;     // rel_shift: t -> j
                if (j >= 0) C[(size_t)m * KLEN + j] += acc[ii][jj];
            } else {
                C[(size_t)m * KLEN + nn] = acc[ii][jj];
            }
        }
    }
}

// ---------------- masked softmax over scores, in place; zero masked tail ----------------
// grid (QLEN, NG)
__global__ __launch_bounds__(256) void k_softmax(float* __restrict__ sA) {
    __shared__ float red[256];
    int i = blockIdx.x;
    int g = blockIdx.y;
    int tid = threadIdx.x;
    float* row = sA + (size_t)g * SROW + (size_t)i * KLEN;
    int len = i + CLEN + MLEN + 1;
    float v[5];
    int cnt = 0;
    float mx = -1e30f;
    for (int j = tid; j < len; j += 256) {
        float s = row[j] * 0.125f;
        v[cnt++] = s;
        mx = fmaxf(mx, s);
    }
    red[tid] = mx;
    __syncthreads();
    for (int st = 128; st > 0; st >>= 1) {
        if (tid < st) red[tid] = fmaxf(red[tid], red[tid + st]);
        __syncthreads();
    }
    float smax = red[0];
    __syncthreads();
    float sum = 0.f;
    cnt = 0;
    for (int j = tid; j < len; j += 256) {
        float e = __expf(v[cnt] - smax);
        v[cnt] = e;
        sum += e;
        cnt++;
    }
    red[tid] = sum;
    __syncthreads();
    for (int st = 128; st > 0; st >>= 1) {
        if (tid < st) red[tid] += red[tid + st];
        __syncthreads();
    }
    float inv = 1.0f / red[0];
    cnt = 0;
    for (int j = tid; j < len; j += 256) row[j] = v[cnt++] * inv;
    for (int j = tid; j < KLEN; j += 256)
        if (j >= len) row[j] = 0.0f;
}

// ---------------- batched AV GEMM (NN, 32x64 tile): attnb = P @ V ----------------
// grid (1, QLEN/32, NG); M=512 rows of P, N=64 dims, K=1056
__global__ __launch_bounds__(256) void k_av_gemm(const float* __restrict__ P,
                                                 const float* __restrict__ heads,
                                                 float* __restrict__ attnb) {
    int g = blockIdx.z;
    int b = g / NH, n = g % NH;
    const float* Ap = P + (size_t)g * SROW;
    const float* Bp = heads + (size_t)b * H3 + 2 * HD + n * DH;   // ldb = BSZ*H3
    float* Cp = attnb + (size_t)b * HD + n * DH;                  // ldc = BSZ*HD
    __shared__ float As[16][33];
    __shared__ float Bs[16][64];
    int tid = threadIdx.x;
    int bm = blockIdx.y * 32;
    int ty = tid >> 4, tx = tid & 15;
    float acc[2][4] = {};
    int arow = tid >> 3, ak = (tid & 7) * 2;
    int bk = tid >> 4, bc = (tid & 15) * 4;
    for (int k0 = 0; k0 < KLEN; k0 += 16) {
        float2 av = *(const float2*)(Ap + (size_t)(bm + arow) * KLEN + k0 + ak);
        float4 bv = *(const float4*)(Bp + (size_t)(k0 + bk) * (BSZ * H3) + bc);
        As[ak + 0][arow] = av.x;
        As[ak + 1][arow] = av.y;
        Bs[bk][bc + 0] = bv.x; Bs[bk][bc + 1] = bv.y;
        Bs[bk][bc + 2] = bv.z; Bs[bk][bc + 3] = bv.w;
        __syncthreads();
#pragma unroll
        for (int kk = 0; kk < 16; kk++) {
            float a0 = As[kk][ty * 2 + 0];
            float a1 = As[kk][ty * 2 + 1];
            float bb[4];
#pragma unroll
            for (int t = 0; t < 4; t++) bb[t] = Bs[kk][tx * 4 + t];
#pragma unroll
            for (int t = 0; t < 4; t++) {
                acc[0][t] += a0 * bb[t];
                acc[1][t] += a1 * bb[t];
            }
        }
        __syncthreads();
    }
#pragma unroll
    for (int ii = 0; ii < 2; ii++) {
        int m = bm + ty * 2 + ii;
#pragma unroll
        for (int jj = 0; jj < 4; jj++) {
            int nn = tx * 4 + jj;
            Cp[(size_t)m * (BSZ * HD) + nn] = acc[ii][jj];
        }
    }
}

// ---------------- h = LN(h + delta) * g + b ----------------
__global__ __launch_bounds__(256) void k_add_ln(float* __restrict__ h,
                                                const float* __restrict__ delta,
                                                const float* __restrict__ g,
                                                const float* __restrict__ bta) {
    __shared__ float xs[DMODEL];
    __shared__ float red[256];
    int row = blockIdx.x;
    int tid = threadIdx.x;
    float* hr = h + (size_t)row * DMODEL;
    const float* dr = delta + (size_t)row * DMODEL;
    float s = 0.f;
    for (int d = tid; d < DMODEL; d += 256) {
        float v = hr[d] + dr[d];
        xs[d] = v;
        s += v;
    }
    red[tid] = s;
    __syncthreads();
    for (int st = 128; st > 0; st >>= 1) {
        if (tid < st) red[tid] += red[tid + st];
        __syncthreads();
    }
    float mean = red[0] * (1.0f / DMODEL);
    __syncthreads();
    float v2 = 0.f;
    for (int d = tid; d < DMODEL; d += 256) {
        float t = xs[d] - mean;
        v2 += t * t;
    }
    red[tid] = v2;
    __syncthreads();
    for (int st = 128; st > 0; st >>= 1) {
        if (tid < st) red[tid] += red[tid + st];
        __syncthreads();
    }
    float inv = rsqrtf(red[0] * (1.0f / DMODEL) + 1e-5f);
    for (int d = tid; d < DMODEL; d += 256) {
        hr[d] = (xs[d] - mean) * inv * g[d] + bta[d];
    }
}

extern "C" void kernel_launch(void* const* d_in, const int* in_sizes, int n_in,
                              void* d_out, int out_size, void* d_ws, size_t ws_size,
                              hipStream_t stream) {
    const int* x = (const int*)d_in[0];
    const float* condition = (const float*)d_in[1];
    const float* mems = (const float*)d_in[2];
    const float* emb = (const float*)d_in[3];
    const float* qkv_w = (const float*)d_in[4];
    const float* r_net_w = (const float*)d_in[5];
    const float* o_w = (const float*)d_in[6];
    const float* ln1_g = (const float*)d_in[7];
    const float* ln1_b = (const float*)d_in[8];
    const float* w1 = (const float*)d_in[9];
    const float* b1 = (const float*)d_in[10];
    const float* w2 = (const float*)d_in[11];
    const float* b2 = (const float*)d_in[12];
    const float* ln2_g = (const float*)d_in[13];
    const float* ln2_b = (const float*)d_in[14];
    const float* r_w_bias = (const float*)d_in[15];
    const float* r_r_bias = (const float*)d_in[16];
    const float* proj_w = (const float*)d_in[17];
    const float* proj_b = (const float*)d_in[18];
    float* out = (float*)d_out;

    float* ws = (float*)d_ws;
    float* h = ws;                                   // 2048*768
    float* rbuf = h + (size_t)MQ * DMODEL;           // 1056*768
    float* rk = rbuf + (size_t)KLEN * DMODEL;        // 1056*768
    float* attnb = rk + (size_t)KLEN * HD;           // 2048*768
    float* cat = attnb + (size_t)MQ * HD;            // 4224*768
    float* heads = cat + (size_t)MK * DMODEL;        // 4224*2304
    float* qw = heads + (size_t)MK * H3;             // 48*512*64
    float* qr = qw + (size_t)NG * QLEN * DH;         // 48*512*64
    float* sA = qr + (size_t)NG * QLEN * DH;         // 48*512*1056 (scores / probs)
    float* delta = cat;                              // reuse (dead during attn epilogue)
    float* ffn = sA;                                 // reuse scores region for FFN hidden

    dim3 blk(256);
    k_embed<<<dim3((MQ * DMODEL + 255) / 256), blk, 0, stream>>>(x, emb, h);
    k_posemb<<<dim3((KLEN * DMODEL + 255) / 256), blk, 0, stream>>>(rbuf);

    for (int l = 0; l < NLAYER; l++) {
        k_concat<<<dim3((MK * DMODEL + 255) / 256), blk, 0, stream>>>(
            condition, mems + (size_t)l * MLEN * BSZ * DMODEL, h, cat);

        // heads = cat @ qkv_w[l]           [4224,2304]
        k_gemm<false, false><<<dim3(H3 / 64, MK / 64), blk, 0, stream>>>(
            cat, qkv_w + (size_t)l * DMODEL * H3, nullptr, heads, MK, H3, DMODEL);

        // rk = r @ r_net_w[l]              [1056,768]
        k_gemm<false, false><<<dim3(HD / 64, (KLEN + 63) / 64), blk, 0, stream>>>(
            rbuf, r_net_w + (size_t)l * DMODEL * HD, nullptr, rk, KLEN, HD, DMODEL);

        // qw/qr = q + biases               [48,512,64] x2
        k_qprep<<<dim3((NG * QLEN * DH + 255) / 256), blk, 0, stream>>>(
            heads, r_w_bias, r_r_bias, qw, qr);

        // sA[g][i][j] = qw . K             (batched NT GEMM, K=64)
        k_bgemm_nt<false><<<dim3((KLEN + 63) / 64, QLEN / 64, NG), blk, 0, stream>>>(
            qw, DH, NH * QLEN * DH, QLEN * DH,
            heads + HD, BSZ * H3, H3, DH,
            sA, QLEN, KLEN, DH);

        // sA[g][i][t-(QLEN-1-i)] += qr . rk (rel_shift fused into epilogue)
        k_bgemm_nt<true><<<dim3((KLEN + 63) / 64, QLEN / 64, NG), blk, 0, stream>>>(
            qr, DH, NH * QLEN * DH, QLEN * DH,
            rk, HD, 0, DH,
            sA, QLEN, KLEN, DH);

        // masked softmax in place (scale 1/8), zero masked tail
        k_softmax<<<dim3(QLEN, NG), blk, 0, stream>>>(sA);

        // attnb = P @ V                    (batched NN GEMM, K=1056)
        k_av_gemm<<<dim3(1, QLEN / 32, NG), blk, 0, stream>>>(sA, heads, attnb);

        // delta = attnb @ o_w[l]           [2048,768]
        k_gemm<false, false><<<dim3(DMODEL / 64, MQ / 64), blk, 0, stream>>>(
            attnb, o_w + (size_t)l * HD * DMODEL, nullptr, delta, MQ, DMODEL, HD);

        // h = LN(h + delta)
        k_add_ln<<<dim3(MQ), blk, 0, stream>>>(h, delta, ln1_g + (size_t)l * DMODEL,
                                               ln1_b + (size_t)l * DMODEL);

        // ffn = relu(h @ w1[l] + b1[l])    [2048,3072]
        k_gemm<true, true><<<dim3(DI / 64, MQ / 64), blk, 0, stream>>>(
            h, w1 + (size_t)l * DMODEL * DI, b1 + (size_t)l * DI, ffn, MQ, DI, DMODEL);

        // delta = ffn @ w2[l] + b2[l]      [2048,768]
        k_gemm<true, false><<<dim3(DMODEL / 64, MQ / 64), blk, 0, stream>>>(
            ffn, w2 + (size_t)l * DI * DMODEL, b2 + (size_t)l * DMODEL, delta, MQ, DMODEL, DI);

        // h = LN(h + delta)
        k_add_ln<<<dim3(MQ), blk, 0, stream>>>(h, delta, ln2_g + (size_t)l * DMODEL,
                                               ln2_b + (size_t)l * DMODEL);
    }

    // out = h @ proj_w + proj_b            [2048,10000]
    k_gemm<true, false><<<dim3((NV + 63) / 64, MQ / 64), blk, 0, stream>>>(
        h, proj_w, proj_b, out, MQ, NV, DMODEL);
}